// Round 6
// baseline (549.313 us; speedup 1.0000x reference)
//
#include <hip/hip_runtime.h>
#include <math.h>

// FHN dynamics — R4 kernel + DEFINITIVE MEASUREMENT PROBE.
// R5's 768-FMA pad (+46.8 us, 0.061 us/FMA calibrated) did NOT surface the
// dispatch -> fhn_baseline <= 116 us. PROBE_PAD 2048 adds ~125 us, putting
// the padded dispatch at 188-241 us — above the 166-us fill ceiling no
// matter where K truly lies. Goal: read per-dispatch FETCH_SIZE/WRITE_SIZE.
//   WRITE ~= 262e3 KB  -> ideal traffic, no eviction overhead (Branch A)
//   WRITE >= 400e3 KB  -> dirty-LLC writeback charged to us (Branch B -> NT stores)
// Memory behavior is byte-identical to R4. Pad removed next round.

#define ROWLEN 2048
#define BLOCK  256
#define EPT    8                 // elements per thread
#define F4PT   (EPT / 4)         // float4 loads per thread = 2
#define PROBE_PAD 2048           // dependent FMAs; ~125 us device-wide (calibrated R5)

__global__ __launch_bounds__(BLOCK)
void fhn_kernel(const float* __restrict__ stim,
                const float* __restrict__ a_p,
                const float* __restrict__ b_p,
                const float* __restrict__ dt_p,
                const int*   __restrict__ nsteps_p,
                float* __restrict__ out,      // [n_elem] response, then [n_elem] v
                long long n_elem)
{
    const long long row = blockIdx.x;
    const float* __restrict__ srow = stim + row * ROWLEN;
    float* __restrict__ rrow = out + row * ROWLEN;
    float* __restrict__ vrow = out + n_elem + row * ROWLEN;

    const int tid = threadIdx.x;

    // ---- coalesced float4 loads: lane t takes float4 slots {t, t+256} ----
    float s[EPT];
    #pragma unroll
    for (int i = 0; i < F4PT; ++i) {
        float4 f = reinterpret_cast<const float4*>(srow)[tid + i * BLOCK];
        s[4*i+0] = f.x; s[4*i+1] = f.y; s[4*i+2] = f.z; s[4*i+3] = f.w;
    }

    // ---- row max(|s|): local -> wave butterfly -> cross-wave via LDS ----
    float m = 0.0f;
    #pragma unroll
    for (int e = 0; e < EPT; ++e) m = fmaxf(m, fabsf(s[e]));
    #pragma unroll
    for (int off = 32; off > 0; off >>= 1)
        m = fmaxf(m, __shfl_xor(m, off, 64));
    __shared__ float smax[BLOCK / 64];
    if ((tid & 63) == 0) smax[tid >> 6] = m;
    __syncthreads();
    m = fmaxf(fmaxf(smax[0], smax[1]), fmaxf(smax[2], smax[3]));

    const float scale     = fmaxf(m, 1e-6f);
    const float inv_scale = 1.0f / scale;

    // ---- scalar params (device-resident 1-element arrays) ----
    const float a  = *a_p;
    const float b  = *b_p;
    const float dt = *dt_p;
    const int   n_steps = *nsteps_p;
    const float alpha     = dt / 12.5f;        // TAU = 12.5
    const float inv_denom = 1.0f / (1.0f + alpha * b);

    // folded step constants
    const float c1 = 1.0f + dt;
    const float c2 = dt * (1.0f / 3.0f);
    const float kw = inv_denom;                // w' = kw*w + k1*vn + k2
    const float k1 = alpha * inv_denom;
    const float k2 = alpha * a * inv_denom;
    const float premul = dt * inv_scale;       // we only ever need dt*I

    // ---- conditioned input current dt*I; v = w = 0 ----
    float dtI[EPT], v[EPT], w[EPT];
    #pragma unroll
    for (int e = 0; e < EPT; ++e) {
        const float as  = fabsf(s[e]);
        const float E   = __expf(fmaf(-10.0f, as, 5.0f));   // exp(-(|s|-0.5)*10)
        const float num = fmaf(0.1f, E, 1.0f);              // 1 + 0.1E
        const float rd  = __builtin_amdgcn_rcpf(1.0f + E);  // ~1ulp, tol=0.0625
        dtI[e] = s[e] * premul * num * rd;                  // s*(0.1+0.9*sig)*dt/scale
        v[e] = 0.0f;
        w[e] = 0.0f;
    }

    // ---- IMEX FHN steps: 8 VALU ops per elem per step ----
    for (int n = 0; n < n_steps; ++n) {
        #pragma unroll
        for (int e = 0; e < EPT; ++e) {
            const float ve = v[e], we = w[e];
            const float t  = ve * ve;                  // v^2
            const float u  = fmaf(-dt, we, dtI[e]);    // dt*I - dt*w
            const float p  = fmaf(c1, ve, u);          // (1+dt)v + ...
            const float q  = c2 * t;                   // (dt/3) v^2
            const float vn = fmaf(-q, ve, p);          // unclipped v_next
            v[e] = fminf(fmaxf(vn, -3.0f), 3.0f);      // med3
            w[e] = fmaf(kw, we, fmaf(k1, vn, k2));     // unclipped vn (matches ref)
        }
    }

    // ---- PROBE PAD: dependent FMA chain, ~125 us device-wide (calibrated).
    {
        float x = scale;
        #pragma unroll
        for (int p = 0; p < PROBE_PAD; ++p)
            x = fmaf(x, 1.0000001f, 1e-30f);
        asm volatile("" :: "v"(x));    // keep live, rule #17
    }

    // ---- epilogue: response = v * scale; also emit v (plain stores) ----
    #pragma unroll
    for (int i = 0; i < F4PT; ++i) {
        float4 r, vv;
        r.x  = v[4*i+0] * scale; r.y  = v[4*i+1] * scale;
        r.z  = v[4*i+2] * scale; r.w  = v[4*i+3] * scale;
        vv.x = v[4*i+0];         vv.y = v[4*i+1];
        vv.z = v[4*i+2];         vv.w = v[4*i+3];
        reinterpret_cast<float4*>(rrow)[tid + i * BLOCK] = r;
        reinterpret_cast<float4*>(vrow)[tid + i * BLOCK] = vv;
    }
}

extern "C" void kernel_launch(void* const* d_in, const int* in_sizes, int n_in,
                              void* d_out, int out_size, void* d_ws, size_t ws_size,
                              hipStream_t stream) {
    const float* stim = (const float*)d_in[0];
    const float* a_p  = (const float*)d_in[1];
    const float* b_p  = (const float*)d_in[2];
    const float* dt_p = (const float*)d_in[3];
    const int*   n_p  = (const int*)d_in[4];
    float* out = (float*)d_out;

    const long long n_elem = (long long)in_sizes[0];
    const int rows = (int)(n_elem / ROWLEN);
    if (rows <= 0) return;

    fhn_kernel<<<rows, BLOCK, 0, stream>>>(stim, a_p, b_p, dt_p, n_p, out, n_elem);
}

// Round 7
// 371.136 us; speedup vs baseline: 1.4801x; 1.4801x over previous
//
#include <hip/hip_runtime.h>
#include <math.h>

// FHN dynamics — persistent software-pipelined block-per-row.
// R6 probe established: traffic is ideal (67 MB fetch + 268 MB write),
// K_true ~= 115 us vs ~55-65 us BW floor. Theory: per-block
// load -> __syncthreads(vmcnt(0) drain!) -> compute -> store serialization
// plus generation convoying. This version:
//  - 2048 persistent blocks (8/CU, all resident), 4 rows each, grid-stride.
//  - Register prefetch of row r+G issued BEFORE computing row r.
//  - Cross-wave max uses raw s_barrier + lgkmcnt(0)-ONLY waits
//    (parity-double-buffered smax) so prefetch vmcnt stays in flight
//    across the barrier — __syncthreads would drain it.
//  - Math identical to R4 (passed, absmax 0.0625).

#define ROWLEN 2048
#define BLOCK  256
#define EPT    8                 // elements per thread
#define F4PT   (EPT / 4)         // float4 loads per thread = 2

typedef float vf4 __attribute__((ext_vector_type(4)));

__global__ __launch_bounds__(BLOCK)
void fhn_kernel(const float* __restrict__ stim,
                const float* __restrict__ a_p,
                const float* __restrict__ b_p,
                const float* __restrict__ dt_p,
                const int*   __restrict__ nsteps_p,
                float* __restrict__ out,      // [n_elem] response, then [n_elem] v
                long long n_elem, int rows)
{
    const int tid = threadIdx.x;
    const int wid = tid >> 6;
    const int G   = gridDim.x;

    __shared__ float smax[2][4];   // parity double-buffered cross-wave max

    // ---- uniform scalar params (loaded once; s_load path) ----
    const float a  = *a_p;
    const float b  = *b_p;
    const float dt = *dt_p;
    const int   n_steps = *nsteps_p;
    const float alpha     = dt / 12.5f;        // TAU = 12.5
    const float inv_denom = 1.0f / (1.0f + alpha * b);
    const float c1 = 1.0f + dt;
    const float c2 = dt * (1.0f / 3.0f);
    const float kw = inv_denom;                // w' = kw*w + k1*vn + k2
    const float k1 = alpha * inv_denom;
    const float k2 = alpha * a * inv_denom;

    // ---- prologue: load first assigned row into cur ----
    vf4 cur0, cur1, nxt0, nxt1;
    {
        const vf4* src = reinterpret_cast<const vf4*>(
            stim + (long long)blockIdx.x * ROWLEN);
        cur0 = src[tid];
        cur1 = src[tid + BLOCK];
    }

    int it = 0;
    for (int row = blockIdx.x; row < rows; row += G, ++it) {
        // ---- prefetch next assigned row (stays in flight across barrier) ----
        const int nrow = row + G;
        if (nrow < rows) {
            const vf4* src = reinterpret_cast<const vf4*>(
                stim + (long long)nrow * ROWLEN);
            nxt0 = src[tid];
            nxt1 = src[tid + BLOCK];
        }

        // ---- row max(|s|): local (cur only -> counted vmcnt) + butterfly ----
        float m = fmaxf(fmaxf(fmaxf(fabsf(cur0.x), fabsf(cur0.y)),
                              fmaxf(fabsf(cur0.z), fabsf(cur0.w))),
                        fmaxf(fmaxf(fabsf(cur1.x), fabsf(cur1.y)),
                              fmaxf(fabsf(cur1.z), fabsf(cur1.w))));
        #pragma unroll
        for (int off = 32; off > 0; off >>= 1)
            m = fmaxf(m, __shfl_xor(m, off, 64));

        // ---- cross-wave max: raw barrier, lgkmcnt-only waits ----
        const int p = it & 1;
        if ((tid & 63) == 0) smax[p][wid] = m;
        asm volatile("s_waitcnt lgkmcnt(0)" ::: "memory");  // LDS write visible
        __builtin_amdgcn_s_barrier();                       // NO vmcnt drain
        asm volatile("" ::: "memory");                      // no LDS-read hoist
        m = fmaxf(fmaxf(smax[p][0], smax[p][1]),
                  fmaxf(smax[p][2], smax[p][3]));
        // WAR on smax[p] is protected by the NEXT iteration's barrier
        // (parity buffer flips each iteration).

        const float scale     = fmaxf(m, 1e-6f);
        const float inv_scale = 1.0f / scale;
        const float premul    = dt * inv_scale;

        // ---- conditioned input current dt*I; v = w = 0 ----
        float s[EPT], dtI[EPT], v[EPT], w[EPT];
        s[0]=cur0.x; s[1]=cur0.y; s[2]=cur0.z; s[3]=cur0.w;
        s[4]=cur1.x; s[5]=cur1.y; s[6]=cur1.z; s[7]=cur1.w;
        #pragma unroll
        for (int e = 0; e < EPT; ++e) {
            const float as  = fabsf(s[e]);
            const float E   = __expf(fmaf(-10.0f, as, 5.0f)); // exp(-(|s|-0.5)*10)
            const float num = fmaf(0.1f, E, 1.0f);            // 1 + 0.1E
            const float rd  = __builtin_amdgcn_rcpf(1.0f + E);
            dtI[e] = s[e] * premul * num * rd;   // s*(0.1+0.9*sig)*dt/scale
            v[e] = 0.0f;
            w[e] = 0.0f;
        }

        // ---- IMEX FHN steps: 8 VALU ops per elem per step ----
        for (int n = 0; n < n_steps; ++n) {
            #pragma unroll
            for (int e = 0; e < EPT; ++e) {
                const float ve = v[e], we = w[e];
                const float t  = ve * ve;
                const float u  = fmaf(-dt, we, dtI[e]);    // dt*I - dt*w
                const float pp = fmaf(c1, ve, u);          // (1+dt)v + ...
                const float q  = c2 * t;                   // (dt/3) v^2
                const float vn = fmaf(-q, ve, pp);         // unclipped v_next
                v[e] = fminf(fmaxf(vn, -3.0f), 3.0f);      // med3
                w[e] = fmaf(kw, we, fmaf(k1, vn, k2));     // unclipped vn (ref)
            }
        }

        // ---- epilogue: response = v*scale; raw v (plain cached stores) ----
        float* rrow = out + (long long)row * ROWLEN;
        float* vrow = out + n_elem + (long long)row * ROWLEN;
        vf4 r0, r1, v0, v1;
        r0.x = v[0]*scale; r0.y = v[1]*scale; r0.z = v[2]*scale; r0.w = v[3]*scale;
        r1.x = v[4]*scale; r1.y = v[5]*scale; r1.z = v[6]*scale; r1.w = v[7]*scale;
        v0.x = v[0]; v0.y = v[1]; v0.z = v[2]; v0.w = v[3];
        v1.x = v[4]; v1.y = v[5]; v1.z = v[6]; v1.w = v[7];
        reinterpret_cast<vf4*>(rrow)[tid]         = r0;
        reinterpret_cast<vf4*>(rrow)[tid + BLOCK] = r1;
        reinterpret_cast<vf4*>(vrow)[tid]         = v0;
        reinterpret_cast<vf4*>(vrow)[tid + BLOCK] = v1;

        // ---- rotate prefetch registers (waits nxt loads, NOT stores) ----
        cur0 = nxt0;
        cur1 = nxt1;
    }
}

extern "C" void kernel_launch(void* const* d_in, const int* in_sizes, int n_in,
                              void* d_out, int out_size, void* d_ws, size_t ws_size,
                              hipStream_t stream) {
    const float* stim = (const float*)d_in[0];
    const float* a_p  = (const float*)d_in[1];
    const float* b_p  = (const float*)d_in[2];
    const float* dt_p = (const float*)d_in[3];
    const int*   n_p  = (const int*)d_in[4];
    float* out = (float*)d_out;

    const long long n_elem = (long long)in_sizes[0];
    const int rows = (int)(n_elem / ROWLEN);
    if (rows <= 0) return;

    // 2048 persistent blocks = 8 blocks/CU on 256 CUs, all co-resident;
    // each block streams rows/2048 rows through the register pipeline.
    int blocks = rows < 2048 ? rows : 2048;

    fhn_kernel<<<blocks, BLOCK, 0, stream>>>(stim, a_p, b_p, dt_p, n_p,
                                             out, n_elem, rows);
}

// Round 8
// 366.618 us; speedup vs baseline: 1.4983x; 1.0123x over previous
//
#include <hip/hip_runtime.h>
#include <math.h>

// FHN dynamics — R4 kernel + SINGLE-VARIABLE CHANGE: nontemporal stores.
// Theory: the ~60 us gap between K (~119 us) and the 336-MB roofline
// (~53 us) is write-allocate (RFO) below the TCC: FETCH/WRITE_SIZE are
// TCC counters and cannot see MALL-level line fills for the 268 MB of
// allocating stores (67 + 268 RFO + 268 wb ~= 600 MB -> ~100+ us at HBM).
// NT stores set the no-allocate/streaming policy -> RFO eliminated.
// out is never re-read in the timed region, so this is semantically free.
// Everything else is byte-identical to R4 (365.6 us, absmax 0.0625).

#define ROWLEN 2048
#define BLOCK  256
#define EPT    8                 // elements per thread
#define F4PT   (EPT / 4)         // float4 loads per thread = 2

typedef float vf4 __attribute__((ext_vector_type(4)));

__global__ __launch_bounds__(BLOCK)
void fhn_kernel(const float* __restrict__ stim,
                const float* __restrict__ a_p,
                const float* __restrict__ b_p,
                const float* __restrict__ dt_p,
                const int*   __restrict__ nsteps_p,
                float* __restrict__ out,      // [n_elem] response, then [n_elem] v
                long long n_elem)
{
    const long long row = blockIdx.x;
    const float* __restrict__ srow = stim + row * ROWLEN;
    float* __restrict__ rrow = out + row * ROWLEN;
    float* __restrict__ vrow = out + n_elem + row * ROWLEN;

    const int tid = threadIdx.x;

    // ---- coalesced float4 loads: lane t takes float4 slots {t, t+256} ----
    float s[EPT];
    #pragma unroll
    for (int i = 0; i < F4PT; ++i) {
        float4 f = reinterpret_cast<const float4*>(srow)[tid + i * BLOCK];
        s[4*i+0] = f.x; s[4*i+1] = f.y; s[4*i+2] = f.z; s[4*i+3] = f.w;
    }

    // ---- row max(|s|): local -> wave butterfly -> cross-wave via LDS ----
    float m = 0.0f;
    #pragma unroll
    for (int e = 0; e < EPT; ++e) m = fmaxf(m, fabsf(s[e]));
    #pragma unroll
    for (int off = 32; off > 0; off >>= 1)
        m = fmaxf(m, __shfl_xor(m, off, 64));
    __shared__ float smax[BLOCK / 64];
    if ((tid & 63) == 0) smax[tid >> 6] = m;
    __syncthreads();
    m = fmaxf(fmaxf(smax[0], smax[1]), fmaxf(smax[2], smax[3]));

    const float scale     = fmaxf(m, 1e-6f);
    const float inv_scale = 1.0f / scale;

    // ---- scalar params (device-resident 1-element arrays) ----
    const float a  = *a_p;
    const float b  = *b_p;
    const float dt = *dt_p;
    const int   n_steps = *nsteps_p;
    const float alpha     = dt / 12.5f;        // TAU = 12.5
    const float inv_denom = 1.0f / (1.0f + alpha * b);

    // folded step constants
    const float c1 = 1.0f + dt;
    const float c2 = dt * (1.0f / 3.0f);
    const float kw = inv_denom;                // w' = kw*w + k1*vn + k2
    const float k1 = alpha * inv_denom;
    const float k2 = alpha * a * inv_denom;
    const float premul = dt * inv_scale;       // we only ever need dt*I

    // ---- conditioned input current dt*I; v = w = 0 ----
    float dtI[EPT], v[EPT], w[EPT];
    #pragma unroll
    for (int e = 0; e < EPT; ++e) {
        const float as  = fabsf(s[e]);
        const float E   = __expf(fmaf(-10.0f, as, 5.0f));   // exp(-(|s|-0.5)*10)
        const float num = fmaf(0.1f, E, 1.0f);              // 1 + 0.1E
        const float rd  = __builtin_amdgcn_rcpf(1.0f + E);  // ~1ulp, tol=0.0625
        dtI[e] = s[e] * premul * num * rd;                  // s*(0.1+0.9*sig)*dt/scale
        v[e] = 0.0f;
        w[e] = 0.0f;
    }

    // ---- IMEX FHN steps: 8 VALU ops per elem per step ----
    for (int n = 0; n < n_steps; ++n) {
        #pragma unroll
        for (int e = 0; e < EPT; ++e) {
            const float ve = v[e], we = w[e];
            const float t  = ve * ve;                  // v^2
            const float u  = fmaf(-dt, we, dtI[e]);    // dt*I - dt*w
            const float p  = fmaf(c1, ve, u);          // (1+dt)v + ...
            const float q  = c2 * t;                   // (dt/3) v^2
            const float vn = fmaf(-q, ve, p);          // unclipped v_next
            v[e] = fminf(fmaxf(vn, -3.0f), 3.0f);      // med3
            w[e] = fmaf(kw, we, fmaf(k1, vn, k2));     // unclipped vn (matches ref)
        }
    }

    // ---- epilogue: response = v * scale; also emit v — NONTEMPORAL stores ----
    vf4* rv = reinterpret_cast<vf4*>(rrow);
    vf4* vv4 = reinterpret_cast<vf4*>(vrow);
    #pragma unroll
    for (int i = 0; i < F4PT; ++i) {
        vf4 r, vvv;
        r.x   = v[4*i+0] * scale; r.y   = v[4*i+1] * scale;
        r.z   = v[4*i+2] * scale; r.w   = v[4*i+3] * scale;
        vvv.x = v[4*i+0];         vvv.y = v[4*i+1];
        vvv.z = v[4*i+2];         vvv.w = v[4*i+3];
        __builtin_nontemporal_store(r,   rv  + tid + i * BLOCK);
        __builtin_nontemporal_store(vvv, vv4 + tid + i * BLOCK);
    }
}

extern "C" void kernel_launch(void* const* d_in, const int* in_sizes, int n_in,
                              void* d_out, int out_size, void* d_ws, size_t ws_size,
                              hipStream_t stream) {
    const float* stim = (const float*)d_in[0];
    const float* a_p  = (const float*)d_in[1];
    const float* b_p  = (const float*)d_in[2];
    const float* dt_p = (const float*)d_in[3];
    const int*   n_p  = (const int*)d_in[4];
    float* out = (float*)d_out;

    const long long n_elem = (long long)in_sizes[0];
    const int rows = (int)(n_elem / ROWLEN);
    if (rows <= 0) return;

    fhn_kernel<<<rows, BLOCK, 0, stream>>>(stim, a_p, b_p, dt_p, n_p, out, n_elem);
}